// Round 11
// baseline (410.880 us; speedup 1.0000x reference)
//
#include <hip/hip_runtime.h>
#include <math.h>

#define N_NODES 50000
#define N_EDGES 400000
#define H_HEADS 8
#define D_HEAD 16
#define R_TYPES 6
#define T_TYPES 4
#define DIM 128
#define BN 16                                      // nodes per GEMM tile
#define MAX_TILES ((N_NODES + BN - 1) / BN + T_TYPES)
#define NKEYS (N_NODES * R_TYPES)                  // 300000 (r,dst) buckets, r-major
#define NBLK_K ((NKEYS + 255) / 256)               // 1172
#define SM_SHIFT 8.0f                              // constant softmax shift
#define MAXB 16                                    // agg edge batch (per node)

// ======================= generic scan pieces =======================

__global__ void k_scanA(const int* __restrict__ cnt, int* __restrict__ offs,
                        int* __restrict__ partial, int n) {
    __shared__ int tmp[256];
    int tid = threadIdx.x;
    int i = blockIdx.x * 256 + tid;
    int v = (i < n) ? cnt[i] : 0;
    tmp[tid] = v;
    __syncthreads();
    for (int o = 1; o < 256; o <<= 1) {
        int t = (tid >= o) ? tmp[tid - o] : 0;
        __syncthreads();
        tmp[tid] += t;
        __syncthreads();
    }
    if (i < n) offs[i] = tmp[tid] - v;           // exclusive within block
    if (tid == 255) partial[blockIdx.x] = tmp[255];
}

// single-block chunked exclusive scan (arbitrary length)
__global__ void k_rscan(int* __restrict__ a, int total) {
    __shared__ int tmp[256];
    __shared__ int carry_s;
    int tid = threadIdx.x;
    if (tid == 0) carry_s = 0;
    __syncthreads();
    for (int base = 0; base < total; base += 256) {
        int i = base + tid;
        int v = (i < total) ? a[i] : 0;
        tmp[tid] = v;
        __syncthreads();
        for (int o = 1; o < 256; o <<= 1) {
            int t = (tid >= o) ? tmp[tid - o] : 0;
            __syncthreads();
            tmp[tid] += t;
            __syncthreads();
        }
        int carry = carry_s;
        if (i < total) a[i] = carry + tmp[tid] - v;   // exclusive
        __syncthreads();
        if (tid == 255) carry_s = carry + tmp[255];
        __syncthreads();
    }
}

// add block offsets AND mirror into the scatter cursor (saves a d2d memcpy)
__global__ void k_scanC2(int* __restrict__ offs, const int* __restrict__ partial,
                         int* __restrict__ cursor, int n) {
    int i = blockIdx.x * 256 + threadIdx.x;
    if (i < n) {
        int v = offs[i] + partial[blockIdx.x];
        offs[i] = v;
        cursor[i] = v;
    }
}

// ======================= r-major (r,dst)-keyed CSR build =======================

__global__ void k_count6(const int* __restrict__ dst, const int* __restrict__ etype,
                         int* __restrict__ deg6, int n) {
    int e = blockIdx.x * blockDim.x + threadIdx.x;
    if (e < n) atomicAdd(&deg6[etype[e] * N_NODES + dst[e]], 1);
}

__global__ void k_scatter6(const int* __restrict__ src, const int* __restrict__ dst,
                           const int* __restrict__ etype, int* __restrict__ cursor6,
                           int* __restrict__ esrc_s, int* __restrict__ edst_s, int n) {
    int e = blockIdx.x * blockDim.x + threadIdx.x;
    if (e < n) {
        int key = etype[e] * N_NODES + dst[e];
        int pos = atomicAdd(&cursor6[key], 1);
        esrc_s[pos] = src[e];
        edst_s[pos] = dst[e];
    }
}

// ======================= node type bucketing (padded 16-node tiles) ===========

__global__ void k_tcount_agg(const int* __restrict__ ntype, int* __restrict__ tcnt,
                             int* __restrict__ wpos, int n) {
    __shared__ int hist[T_TYPES];
    __shared__ int base[T_TYPES];
    int tid = threadIdx.x;
    if (tid < T_TYPES) hist[tid] = 0;
    __syncthreads();
    int i = blockIdx.x * 256 + tid;
    int t = 0, rank = 0;
    if (i < n) {
        t = ntype[i];
        rank = atomicAdd(&hist[t], 1);
    }
    __syncthreads();
    if (tid < T_TYPES)
        base[tid] = (hist[tid] > 0) ? atomicAdd(&tcnt[tid], hist[tid]) : 0;
    __syncthreads();
    if (i < n) wpos[i] = base[t] + rank;
}

__global__ void k_tsetup(const int* __restrict__ tcnt, int* __restrict__ pbase,
                         int* __restrict__ ntiles_g, int* __restrict__ tile_type) {
    __shared__ int off[T_TYPES + 1];
    if (threadIdx.x == 0) {
        int o = 0;
        for (int t = 0; t < T_TYPES; ++t) {
            off[t] = o;
            pbase[t] = o * BN;
            o += (tcnt[t] + BN - 1) / BN;
        }
        off[T_TYPES] = o;
        *ntiles_g = o;
    }
    __syncthreads();
    int total = off[T_TYPES];
    for (int i = threadIdx.x; i < total; i += blockDim.x) {
        int t = 0;
        while (t < T_TYPES - 1 && i >= off[t + 1]) ++t;
        tile_type[i] = t;
    }
}

__global__ void k_tscatter2(const int* __restrict__ ntype, const int* __restrict__ wpos,
                            const int* __restrict__ pbase, int* __restrict__ nlist, int n) {
    int i = blockIdx.x * 256 + threadIdx.x;
    if (i < n) nlist[pbase[ntype[i]] + wpos[i]] = i;
}

// ======================= K1: tiled typed-linear k,q,v (v3) =======================

__global__ __launch_bounds__(192) void k_kqv_gemm3(
    const float* __restrict__ x, const int* __restrict__ nlist,
    const int* __restrict__ tile_type, const int* __restrict__ ntiles_g,
    const float* __restrict__ Wk, const float* __restrict__ Wq,
    const float* __restrict__ Wv,
    float* __restrict__ kb, float* __restrict__ qb, float* __restrict__ vb) {
    __shared__ float xs[BN][DIM];   // 8 KB
    __shared__ int sids[BN];
    int b = blockIdx.x;
    if (b >= *ntiles_g) return;
    int tid = threadIdx.x;
    if (tid < BN) sids[tid] = nlist[b * BN + tid];
    __syncthreads();
    for (int idx = tid; idx < BN * (DIM / 4); idx += 192) {
        int row = idx >> 5;
        int q4 = idx & 31;
        int nid = sids[row];
        float4 v4 = make_float4(0.f, 0.f, 0.f, 0.f);
        if (nid >= 0) v4 = *(const float4*)(x + (size_t)nid * DIM + q4 * 4);
        *(float4*)(&xs[row][q4 * 4]) = v4;
    }
    __syncthreads();
    int lt = tid / 96;            // node half: rows lt*8 .. lt*8+7
    int wi = tid % 96;
    int mat = wi >> 5;            // 0=k 1=q 2=v
    int colq = wi & 31;
    int t = tile_type[b];
    const float* W = (mat == 0 ? Wk : (mat == 1 ? Wq : Wv))
                     + (size_t)t * DIM * DIM + colq * 4;
    float acc[8][4];
#pragma unroll
    for (int n = 0; n < 8; ++n) {
        acc[n][0] = 0.f; acc[n][1] = 0.f; acc[n][2] = 0.f; acc[n][3] = 0.f;
    }
    const float* xbase = &xs[lt * 8][0];
    for (int dq = 0; dq < 32; ++dq) {
        float4 w0 = *(const float4*)(W + (size_t)(dq * 4 + 0) * DIM);
        float4 w1 = *(const float4*)(W + (size_t)(dq * 4 + 1) * DIM);
        float4 w2 = *(const float4*)(W + (size_t)(dq * 4 + 2) * DIM);
        float4 w3 = *(const float4*)(W + (size_t)(dq * 4 + 3) * DIM);
#pragma unroll
        for (int n = 0; n < 8; ++n) {
            float4 xv = *(const float4*)(xbase + n * DIM + dq * 4);
            acc[n][0] = fmaf(xv.x, w0.x, acc[n][0]);
            acc[n][0] = fmaf(xv.y, w1.x, acc[n][0]);
            acc[n][0] = fmaf(xv.z, w2.x, acc[n][0]);
            acc[n][0] = fmaf(xv.w, w3.x, acc[n][0]);
            acc[n][1] = fmaf(xv.x, w0.y, acc[n][1]);
            acc[n][1] = fmaf(xv.y, w1.y, acc[n][1]);
            acc[n][1] = fmaf(xv.z, w2.y, acc[n][1]);
            acc[n][1] = fmaf(xv.w, w3.y, acc[n][1]);
            acc[n][2] = fmaf(xv.x, w0.z, acc[n][2]);
            acc[n][2] = fmaf(xv.y, w1.z, acc[n][2]);
            acc[n][2] = fmaf(xv.z, w2.z, acc[n][2]);
            acc[n][2] = fmaf(xv.w, w3.z, acc[n][2]);
            acc[n][3] = fmaf(xv.x, w0.w, acc[n][3]);
            acc[n][3] = fmaf(xv.y, w1.w, acc[n][3]);
            acc[n][3] = fmaf(xv.z, w2.w, acc[n][3]);
            acc[n][3] = fmaf(xv.w, w3.w, acc[n][3]);
        }
    }
    float* ob = (mat == 0 ? kb : (mat == 1 ? qb : vb));
#pragma unroll
    for (int n = 0; n < 8; ++n) {
        int nid = sids[lt * 8 + n];
        if (nid >= 0)
            *(float4*)(ob + (size_t)nid * DIM + colq * 4) =
                make_float4(acc[n][0], acc[n][1], acc[n][2], acc[n][3]);
    }
}

// ======================= K2: per-edge attention logits (v3) =============

__global__ __launch_bounds__(256) void k_edge_a3(
    const float* __restrict__ kbuf, const float* __restrict__ qbuf,
    const int* __restrict__ esrc_s, const int* __restrict__ edst_s,
    const int* __restrict__ beg6,
    const float* __restrict__ rel_att, const float* __restrict__ rel_pri,
    float* __restrict__ a_ws, int nE) {
    __shared__ float A2[2][8 * 260];   // 2 r-slots, 8 heads, 16x16 each (stride 260)
    __shared__ float pri[2][8];
    __shared__ int rb_s[R_TYPES + 1];
    __shared__ int r01[2];
    int b = blockIdx.x;
    int e0 = b * 32;
    int tid = threadIdx.x;
    int nHere = nE - e0; if (nHere > 32) nHere = 32;
    if (nHere <= 0) return;
    if (tid < R_TYPES) rb_s[tid] = beg6[tid * N_NODES];   // start of relation r
    if (tid == R_TYPES) rb_s[R_TYPES] = nE;
    __syncthreads();
    if (tid == 0) {
        int rA = 0, rB = 0;
        int eL = e0 + nHere - 1;
#pragma unroll
        for (int r = 1; r < R_TYPES; ++r) {
            if (e0 >= rb_s[r]) rA = r;
            if (eL >= rb_s[r]) rB = r;
        }
        r01[0] = rA; r01[1] = rB;
    }
    __syncthreads();
    int r0 = r01[0], r1 = r01[1];
    int bnd = rb_s[r0 + 1];                   // entries >= bnd belong to r1
    for (int idx = tid; idx < 2 * 2048; idx += 256) {
        int slot = idx >> 11;
        if (slot == 1 && r1 == r0) break;
        int rem = idx & 2047;
        int h = rem >> 8, dj = rem & 255;
        int rr = slot ? r1 : r0;
        A2[slot][h * 260 + dj] = rel_att[(h * R_TYPES + rr) * 256 + dj];
    }
    if (tid < 16) {
        int slot = tid >> 3, h = tid & 7;
        pri[slot][h] = rel_pri[h * R_TYPES + (slot ? r1 : r0)] * 0.25f;
    }
    __syncthreads();
    int el = tid >> 3;
    int h  = tid & 7;
    int q2 = e0 + el;
    if (q2 >= nE) return;
    int s = esrc_s[q2], dn = edst_s[q2];
    int slot = (q2 >= bnd) ? 1 : 0;
    const float4* kp = (const float4*)(kbuf + (size_t)s  * DIM + h * 16);
    const float4* qp = (const float4*)(qbuf + (size_t)dn * DIM + h * 16);
    float4 k4[4], q4[4];
#pragma unroll
    for (int i = 0; i < 4; ++i) { k4[i] = kp[i]; q4[i] = qp[i]; }
    float kk[16] = {k4[0].x,k4[0].y,k4[0].z,k4[0].w, k4[1].x,k4[1].y,k4[1].z,k4[1].w,
                    k4[2].x,k4[2].y,k4[2].z,k4[2].w, k4[3].x,k4[3].y,k4[3].z,k4[3].w};
    float qq[16] = {q4[0].x,q4[0].y,q4[0].z,q4[0].w, q4[1].x,q4[1].y,q4[1].z,q4[1].w,
                    q4[2].x,q4[2].y,q4[2].z,q4[2].w, q4[3].x,q4[3].y,q4[3].z,q4[3].w};
    const float4* A4 = (const float4*)&A2[slot][h * 260];
    float accj[16];
#pragma unroll
    for (int j = 0; j < 16; ++j) accj[j] = 0.f;
#pragma unroll
    for (int d = 0; d < 16; ++d) {
        float kd = kk[d];
#pragma unroll
        for (int jj = 0; jj < 4; ++jj) {
            float4 a4 = A4[d * 4 + jj];
            accj[jj * 4 + 0] = fmaf(kd, a4.x, accj[jj * 4 + 0]);
            accj[jj * 4 + 1] = fmaf(kd, a4.y, accj[jj * 4 + 1]);
            accj[jj * 4 + 2] = fmaf(kd, a4.z, accj[jj * 4 + 2]);
            accj[jj * 4 + 3] = fmaf(kd, a4.w, accj[jj * 4 + 3]);
        }
    }
    float acc = 0.f;
#pragma unroll
    for (int j = 0; j < 16; ++j) acc = fmaf(accj[j], qq[j], acc);
    a_ws[(size_t)q2 * 8 + h] = acc * pri[slot][h];   // coalesced (own position)
}

// ======================= K3: per-node softmax + aggregation (v9) ==============
// 128 thr/node = 2 SLOTS x 64 lanes; each slot walks alternating edges with
// float2 v-loads (64x8B = full row). 2 nodes x 2 slots = 4 independent edge
// streams per block, straight-line body (6-way register select, no branches,
// no LDS writes in loop) -> compiler can keep ~16 loads in flight.

__global__ __launch_bounds__(256) void k_aggregate9(
    const float* __restrict__ vbuf, const float* __restrict__ a_ws,
    const int* __restrict__ beg6, const int* __restrict__ esrc_s,
    const float* __restrict__ rel_msg,
    float* __restrict__ hacc, int n, int nE) {
    __shared__ float wsum[2][2][R_TYPES][DIM];   // 12 KB [node][slot][r][elem]
    __shared__ float den_s[2][2][H_HEADS];
    __shared__ float exl[2][MAXB][H_HEADS];      // 1 KB
    __shared__ int   sl[2][MAXB];
    __shared__ int   bb[2][2 * R_TYPES];
    __shared__ int   cum[2][R_TYPES + 1];
    __shared__ int   rl[2][MAXB];
    __shared__ int   dgmax_s;
    int tid = threadIdx.x;
    int nb = tid >> 7;
    int lane2 = tid & 127;
    int slot = lane2 >> 6;      // 0/1 (each slot = one aligned 64-lane wave)
    int l    = lane2 & 63;      // covers elems 2l, 2l+1
    int node = blockIdx.x * 2 + nb;
    bool valid = node < n;
    int h = lane2 >> 4;         // epilogue mapping
    int d = lane2 & 15;
    if (lane2 < 2 * R_TYPES) {
        int rr = lane2 >= R_TYPES ? lane2 - R_TYPES : lane2;
        int key = rr * N_NODES + (valid ? node : 0);
        int val;
        if (lane2 < R_TYPES) val = valid ? beg6[key] : 0;
        else                 val = valid ? ((key + 1 < NKEYS) ? beg6[key + 1] : nE) : 0;
        bb[nb][lane2] = val;
    }
    if (tid == 0) dgmax_s = 0;
    __syncthreads();
    if (lane2 == 0) {
        int c = 0;
#pragma unroll
        for (int rr = 0; rr < R_TYPES; ++rr) {
            cum[nb][rr] = c;
            c += bb[nb][R_TYPES + rr] - bb[nb][rr];
        }
        cum[nb][R_TYPES] = c;
        atomicMax(&dgmax_s, c);
    }
    __syncthreads();
    int dg = cum[nb][R_TYPES];
    int dgmax = dgmax_s;

    // register accumulators: per-r float2
    float2 accR[R_TYPES];
#pragma unroll
    for (int rr = 0; rr < R_TYPES; ++rr) accR[rr] = make_float2(0.f, 0.f);
    float den = 0.f;
    int hh = l >> 3;            // head of my element pair (slot-lane view)
    int js = lane2 >> 3;        // staging edge slot 0..15
    int hs = lane2 & 7;         // staging head

    for (int base = 0; base < dgmax; base += MAXB) {
        __syncthreads();
        // ---- stage up to 16 edges: exp(a) in parallel, src, r ----
        int jj = base + js;
        if (jj < dg) {
            int rr = 0;
#pragma unroll
            for (int q = 1; q < R_TYPES; ++q) if (jj >= cum[nb][q]) rr = q;
            int p = bb[nb][rr] + (jj - cum[nb][rr]);
            exl[nb][js][hs] = __expf(a_ws[(size_t)p * 8 + hs] - SM_SHIFT);
            if (hs == 0) { sl[nb][js] = esrc_s[p]; rl[nb][js] = rr; }
        }
        __syncthreads();
        // ---- accumulate: slot handles local edges slot, slot+2, ... ----
        int cnt = dg - base; if (cnt > MAXB) cnt = MAXB; if (cnt < 0) cnt = 0;
#pragma unroll 4
        for (int j = slot; j < cnt; j += 2) {
            float ex = exl[nb][j][hh];
            int   s  = sl[nb][j];
            int   r  = rl[nb][j];
            float2 vv = *(const float2*)(vbuf + (size_t)s * DIM + 2 * l);
            den += ex;
            float ax = ex * vv.x, ay = ex * vv.y;
#pragma unroll
            for (int rr = 0; rr < R_TYPES; ++rr) {
                accR[rr].x += (rr == r) ? ax : 0.f;
                accR[rr].y += (rr == r) ? ay : 0.f;
            }
        }
    }
    // flush buckets + dens
#pragma unroll
    for (int rr = 0; rr < R_TYPES; ++rr) {
        wsum[nb][slot][rr][2 * l]     = accR[rr].x;
        wsum[nb][slot][rr][2 * l + 1] = accR[rr].y;
    }
    if ((l & 7) == 0) den_s[nb][slot][hh] = den;   // all 8 lanes hold slot den
    __syncthreads();

    // epilogue: out[h][d] = (1/den) * sum_r sum_dp (b0+b1)[r][h*16+dp] * M[h][r][dp][d]
    float dtot = den_s[nb][0][h] + den_s[nb][1][h];
    float acc = 0.f;
#pragma unroll
    for (int rr = 0; rr < R_TYPES; ++rr) {
        const float*  M  = rel_msg + ((size_t)h * R_TYPES + rr) * 256;
        const float4* b0 = (const float4*)&wsum[nb][0][rr][h * 16];
        const float4* b1 = (const float4*)&wsum[nb][1][rr][h * 16];
#pragma unroll
        for (int dq = 0; dq < 4; ++dq) {
            float4 v0 = b0[dq];
            float4 v1 = b1[dq];
            acc = fmaf(v0.x + v1.x, M[(dq * 4 + 0) * 16 + d], acc);
            acc = fmaf(v0.y + v1.y, M[(dq * 4 + 1) * 16 + d], acc);
            acc = fmaf(v0.z + v1.z, M[(dq * 4 + 2) * 16 + d], acc);
            acc = fmaf(v0.w + v1.w, M[(dq * 4 + 3) * 16 + d], acc);
        }
    }
    if (valid)
        hacc[(size_t)node * DIM + lane2] = acc / fmaxf(dtot, 1e-9f);
}

// ======================= K4: tiled Wa + gate + residual + LayerNorm ===========

__global__ __launch_bounds__(256) void k_final_gemm(
    const float* __restrict__ x, const int* __restrict__ nlist,
    const int* __restrict__ tile_type, const int* __restrict__ ntiles_g,
    const float* __restrict__ Wa, const float* __restrict__ skip,
    const float* __restrict__ gamma, const float* __restrict__ beta,
    float* __restrict__ out) {
    __shared__ float hs[BN][DIM];
    __shared__ float ys[BN][DIM];
    __shared__ int sids[BN];
    __shared__ float mred[BN], ired[BN];
    int b = blockIdx.x;
    if (b >= *ntiles_g) return;
    int tid = threadIdx.x;
    if (tid < BN) sids[tid] = nlist[b * BN + tid];
    __syncthreads();
    for (int idx = tid; idx < BN * DIM; idx += 256) {
        int row = idx >> 7, col = idx & 127;
        int nid = sids[row];
        hs[row][col] = (nid >= 0) ? out[(size_t)nid * DIM + col] : 0.f;
    }
    __syncthreads();
    int t = tile_type[b];
    int half = tid >> 7, col = tid & 127;
    const float* W = Wa + (size_t)t * DIM * DIM;
    float acc[8];
#pragma unroll
    for (int n = 0; n < 8; ++n) acc[n] = 0.f;
#pragma unroll 4
    for (int d = 0; d < DIM; ++d) {
        float w = W[d * DIM + col];
#pragma unroll
        for (int n = 0; n < 8; ++n) acc[n] = fmaf(hs[half * 8 + n][d], w, acc[n]);
    }
    float gte = 1.f / (1.f + __expf(-skip[t]));
#pragma unroll
    for (int n = 0; n < 8; ++n) {
        int row = half * 8 + n;
        int nid = sids[row];
        float xv = (nid >= 0) ? x[(size_t)nid * DIM + col] : 0.f;
        ys[row][col] = xv * (2.f - gte) + acc[n] * gte;
    }
    __syncthreads();
    int ng = tid >> 4, l16 = tid & 15;
    float s = 0.f, s2 = 0.f;
#pragma unroll
    for (int k2 = 0; k2 < 8; ++k2) {
        float yv = ys[ng][l16 + 16 * k2];
        s += yv; s2 += yv * yv;
    }
#pragma unroll
    for (int m = 1; m < 16; m <<= 1) {
        s  += __shfl_xor(s, m, 64);
        s2 += __shfl_xor(s2, m, 64);
    }
    if (l16 == 0) {
        float mu = s * (1.f / DIM);
        float var = s2 * (1.f / DIM) - mu * mu;
        mred[ng] = mu;
        ired[ng] = rsqrtf(var + 1e-5f);
    }
    __syncthreads();
    float gm = gamma[col], bt = beta[col];
#pragma unroll
    for (int n = 0; n < 8; ++n) {
        int row = half * 8 + n;
        int nid = sids[row];
        if (nid >= 0)
            out[(size_t)nid * DIM + col] = (ys[row][col] - mred[row]) * ired[row] * gm + bt;
    }
}

// ======================= launcher =======================

extern "C" void kernel_launch(void* const* d_in, const int* in_sizes, int n_in,
                              void* d_out, int out_size, void* d_ws, size_t ws_size,
                              hipStream_t stream) {
    const float* x       = (const float*)d_in[0];
    const int*   src     = (const int*)d_in[1];
    const int*   dst     = (const int*)d_in[2];
    const int*   ntype   = (const int*)d_in[3];
    const int*   etype   = (const int*)d_in[4];
    const float* Wk      = (const float*)d_in[5];
    const float* Wq      = (const float*)d_in[6];
    const float* Wv      = (const float*)d_in[7];
    const float* Wa      = (const float*)d_in[8];
    const float* rel_pri = (const float*)d_in[9];
    const float* rel_att = (const float*)d_in[10];
    const float* rel_msg = (const float*)d_in[11];
    const float* skip    = (const float*)d_in[12];
    const float* gamma   = (const float*)d_in[13];
    const float* beta    = (const float*)d_in[14];
    float* out = (float*)d_out;

    const int N = N_NODES, E = N_EDGES;

    // workspace layout
    char* ws = (char*)d_ws;
    float* kb   = (float*)ws;                          // N*128
    float* qb   = kb + (size_t)N * DIM;                // N*128
    float* vb   = qb + (size_t)N * DIM;                // N*128
    float* a_ws = vb + (size_t)N * DIM;                // E*8
    int* deg6    = (int*)(a_ws + (size_t)E * H_HEADS); // NKEYS
    int* beg6    = deg6 + NKEYS;                       // NKEYS
    int* cursor6 = beg6 + NKEYS;                       // NKEYS
    int* partial6 = cursor6 + NKEYS;                   // NBLK_K
    int* esrc_s  = partial6 + NBLK_K;                  // E
    int* edst_s  = esrc_s + E;                         // E
    int* tcnt    = edst_s + E;                         // 4
    int* pbase   = tcnt + T_TYPES;                     // 4
    int* ntiles  = pbase + T_TYPES;                    // 1
    int* tile_type = ntiles + 1;                       // MAX_TILES
    int* nlist   = tile_type + MAX_TILES;              // MAX_TILES*BN
    int* wpos    = nlist + (size_t)MAX_TILES * BN;     // N

    const int nbScan = (N + 255) / 256;

    // r-major (r,dst)-keyed CSR build (single sort serves edge_a AND aggregate)
    hipMemsetAsync(deg6, 0, (size_t)NKEYS * sizeof(int), stream);
    k_count6<<<(E + 255) / 256, 256, 0, stream>>>(dst, etype, deg6, E);
    k_scanA<<<NBLK_K, 256, 0, stream>>>(deg6, beg6, partial6, NKEYS);
    k_rscan<<<1, 256, 0, stream>>>(partial6, NBLK_K);
    k_scanC2<<<NBLK_K, 256, 0, stream>>>(beg6, partial6, cursor6, NKEYS);
    k_scatter6<<<(E + 255) / 256, 256, 0, stream>>>(
        src, dst, etype, cursor6, esrc_s, edst_s, E);

    // node type buckets (padded 16-node tiles)
    hipMemsetAsync(tcnt, 0, T_TYPES * sizeof(int), stream);
    k_tcount_agg<<<nbScan, 256, 0, stream>>>(ntype, tcnt, wpos, N);
    k_tsetup<<<1, 256, 0, stream>>>(tcnt, pbase, ntiles, tile_type);
    hipMemsetAsync(nlist, 0xFF, (size_t)MAX_TILES * BN * sizeof(int), stream);
    k_tscatter2<<<nbScan, 256, 0, stream>>>(ntype, wpos, pbase, nlist, N);

    // projections (tiled per-type GEMM, full-chip grid)
    k_kqv_gemm3<<<MAX_TILES, 192, 0, stream>>>(
        x, nlist, tile_type, ntiles, Wk, Wq, Wv, kb, qb, vb);

    // edge logits (r-sorted by construction, coalesced a_ws write)
    k_edge_a3<<<(E + 31) / 32, 256, 0, stream>>>(
        kb, qb, esrc_s, edst_s, beg6, rel_att, rel_pri, a_ws, E);

    // per-node softmax + message aggregation -> d_out (scratch)
    k_aggregate9<<<(N + 1) / 2, 256, 0, stream>>>(
        vb, a_ws, beg6, esrc_s, rel_msg, out, N, E);

    // output projection + gate + residual + LayerNorm (in place on d_out)
    k_final_gemm<<<MAX_TILES, 256, 0, stream>>>(
        x, nlist, tile_type, ntiles, Wa, skip, gamma, beta, out);
}

// Round 12
// 386.533 us; speedup vs baseline: 1.0630x; 1.0630x over previous
//
#include <hip/hip_runtime.h>
#include <math.h>

#define N_NODES 50000
#define N_EDGES 400000
#define H_HEADS 8
#define D_HEAD 16
#define R_TYPES 6
#define T_TYPES 4
#define DIM 128
#define BN 16                                      // nodes per GEMM tile
#define MAX_TILES ((N_NODES + BN - 1) / BN + T_TYPES)
#define NKEYS (N_NODES * R_TYPES)                  // 300000 (r,dst) buckets, r-major
#define NBLK_K ((NKEYS + 255) / 256)               // 1172
#define SM_SHIFT 8.0f                              // constant softmax shift
#define MAXB 16                                    // agg edge batch (per node)

typedef unsigned short bf16_t;

__device__ __forceinline__ float bf2f(bf16_t u) {
    unsigned int v = ((unsigned int)u) << 16;
    return __int_as_float((int)v);
}
__device__ __forceinline__ bf16_t f2bf(float f) {
    unsigned int u = (unsigned int)__float_as_int(f);
    unsigned int lsb = (u >> 16) & 1u;
    u += 0x7fffu + lsb;                            // round-to-nearest-even
    return (bf16_t)(u >> 16);
}
__device__ __forceinline__ void bf2x(unsigned int u, float& a, float& b) {
    a = bf2f((bf16_t)(u & 0xffffu));
    b = bf2f((bf16_t)(u >> 16));
}

// ======================= generic scan pieces =======================

__global__ void k_scanA(const int* __restrict__ cnt, int* __restrict__ offs,
                        int* __restrict__ partial, int n) {
    __shared__ int tmp[256];
    int tid = threadIdx.x;
    int i = blockIdx.x * 256 + tid;
    int v = (i < n) ? cnt[i] : 0;
    tmp[tid] = v;
    __syncthreads();
    for (int o = 1; o < 256; o <<= 1) {
        int t = (tid >= o) ? tmp[tid - o] : 0;
        __syncthreads();
        tmp[tid] += t;
        __syncthreads();
    }
    if (i < n) offs[i] = tmp[tid] - v;           // exclusive within block
    if (tid == 255) partial[blockIdx.x] = tmp[255];
}

__global__ void k_rscan(int* __restrict__ a, int total) {
    __shared__ int tmp[256];
    __shared__ int carry_s;
    int tid = threadIdx.x;
    if (tid == 0) carry_s = 0;
    __syncthreads();
    for (int base = 0; base < total; base += 256) {
        int i = base + tid;
        int v = (i < total) ? a[i] : 0;
        tmp[tid] = v;
        __syncthreads();
        for (int o = 1; o < 256; o <<= 1) {
            int t = (tid >= o) ? tmp[tid - o] : 0;
            __syncthreads();
            tmp[tid] += t;
            __syncthreads();
        }
        int carry = carry_s;
        if (i < total) a[i] = carry + tmp[tid] - v;   // exclusive
        __syncthreads();
        if (tid == 255) carry_s = carry + tmp[255];
        __syncthreads();
    }
}

__global__ void k_scanC2(int* __restrict__ offs, const int* __restrict__ partial,
                         int* __restrict__ cursor, int n) {
    int i = blockIdx.x * 256 + threadIdx.x;
    if (i < n) {
        int v = offs[i] + partial[blockIdx.x];
        offs[i] = v;
        cursor[i] = v;
    }
}

// ======================= r-major (r,dst)-keyed CSR build =======================

__global__ void k_count6(const int* __restrict__ dst, const int* __restrict__ etype,
                         int* __restrict__ deg6, int n) {
    int e = blockIdx.x * blockDim.x + threadIdx.x;
    if (e < n) atomicAdd(&deg6[etype[e] * N_NODES + dst[e]], 1);
}

__global__ void k_scatter6(const int* __restrict__ src, const int* __restrict__ dst,
                           const int* __restrict__ etype, int* __restrict__ cursor6,
                           int* __restrict__ esrc_s, int* __restrict__ edst_s, int n) {
    int e = blockIdx.x * blockDim.x + threadIdx.x;
    if (e < n) {
        int key = etype[e] * N_NODES + dst[e];
        int pos = atomicAdd(&cursor6[key], 1);
        esrc_s[pos] = src[e];
        edst_s[pos] = dst[e];
    }
}

// ======================= node type bucketing (padded 16-node tiles) ===========

__global__ void k_tcount_agg(const int* __restrict__ ntype, int* __restrict__ tcnt,
                             int* __restrict__ wpos, int n) {
    __shared__ int hist[T_TYPES];
    __shared__ int base[T_TYPES];
    int tid = threadIdx.x;
    if (tid < T_TYPES) hist[tid] = 0;
    __syncthreads();
    int i = blockIdx.x * 256 + tid;
    int t = 0, rank = 0;
    if (i < n) {
        t = ntype[i];
        rank = atomicAdd(&hist[t], 1);
    }
    __syncthreads();
    if (tid < T_TYPES)
        base[tid] = (hist[tid] > 0) ? atomicAdd(&tcnt[tid], hist[tid]) : 0;
    __syncthreads();
    if (i < n) wpos[i] = base[t] + rank;
}

__global__ void k_tsetup(const int* __restrict__ tcnt, int* __restrict__ pbase,
                         int* __restrict__ ntiles_g, int* __restrict__ tile_type) {
    __shared__ int off[T_TYPES + 1];
    if (threadIdx.x == 0) {
        int o = 0;
        for (int t = 0; t < T_TYPES; ++t) {
            off[t] = o;
            pbase[t] = o * BN;
            o += (tcnt[t] + BN - 1) / BN;
        }
        off[T_TYPES] = o;
        *ntiles_g = o;
    }
    __syncthreads();
    int total = off[T_TYPES];
    for (int i = threadIdx.x; i < total; i += blockDim.x) {
        int t = 0;
        while (t < T_TYPES - 1 && i >= off[t + 1]) ++t;
        tile_type[i] = t;
    }
}

__global__ void k_tscatter2(const int* __restrict__ ntype, const int* __restrict__ wpos,
                            const int* __restrict__ pbase, int* __restrict__ nlist, int n) {
    int i = blockIdx.x * 256 + threadIdx.x;
    if (i < n) nlist[pbase[ntype[i]] + wpos[i]] = i;
}

// ======================= K1: tiled typed-linear k,q,v (v4, bf16 out) ==========
// One 16-node tile per block, 192 threads = 2 node-halves x 3 mats x 32 col-quads.
// f32 compute, bf16 (RNE) outputs -> halves all downstream gather traffic.

__global__ __launch_bounds__(192) void k_kqv_gemm4(
    const float* __restrict__ x, const int* __restrict__ nlist,
    const int* __restrict__ tile_type, const int* __restrict__ ntiles_g,
    const float* __restrict__ Wk, const float* __restrict__ Wq,
    const float* __restrict__ Wv,
    bf16_t* __restrict__ kb, bf16_t* __restrict__ qb, bf16_t* __restrict__ vb) {
    __shared__ float xs[BN][DIM];   // 8 KB
    __shared__ int sids[BN];
    int b = blockIdx.x;
    if (b >= *ntiles_g) return;
    int tid = threadIdx.x;
    if (tid < BN) sids[tid] = nlist[b * BN + tid];
    __syncthreads();
    for (int idx = tid; idx < BN * (DIM / 4); idx += 192) {
        int row = idx >> 5;
        int q4 = idx & 31;
        int nid = sids[row];
        float4 v4 = make_float4(0.f, 0.f, 0.f, 0.f);
        if (nid >= 0) v4 = *(const float4*)(x + (size_t)nid * DIM + q4 * 4);
        *(float4*)(&xs[row][q4 * 4]) = v4;
    }
    __syncthreads();
    int lt = tid / 96;            // node half: rows lt*8 .. lt*8+7
    int wi = tid % 96;
    int mat = wi >> 5;            // 0=k 1=q 2=v
    int colq = wi & 31;
    int t = tile_type[b];
    const float* W = (mat == 0 ? Wk : (mat == 1 ? Wq : Wv))
                     + (size_t)t * DIM * DIM + colq * 4;
    float acc[8][4];
#pragma unroll
    for (int n = 0; n < 8; ++n) {
        acc[n][0] = 0.f; acc[n][1] = 0.f; acc[n][2] = 0.f; acc[n][3] = 0.f;
    }
    const float* xbase = &xs[lt * 8][0];
    for (int dq = 0; dq < 32; ++dq) {
        float4 w0 = *(const float4*)(W + (size_t)(dq * 4 + 0) * DIM);
        float4 w1 = *(const float4*)(W + (size_t)(dq * 4 + 1) * DIM);
        float4 w2 = *(const float4*)(W + (size_t)(dq * 4 + 2) * DIM);
        float4 w3 = *(const float4*)(W + (size_t)(dq * 4 + 3) * DIM);
#pragma unroll
        for (int n = 0; n < 8; ++n) {
            float4 xv = *(const float4*)(xbase + n * DIM + dq * 4);
            acc[n][0] = fmaf(xv.x, w0.x, acc[n][0]);
            acc[n][0] = fmaf(xv.y, w1.x, acc[n][0]);
            acc[n][0] = fmaf(xv.z, w2.x, acc[n][0]);
            acc[n][0] = fmaf(xv.w, w3.x, acc[n][0]);
            acc[n][1] = fmaf(xv.x, w0.y, acc[n][1]);
            acc[n][1] = fmaf(xv.y, w1.y, acc[n][1]);
            acc[n][1] = fmaf(xv.z, w2.y, acc[n][1]);
            acc[n][1] = fmaf(xv.w, w3.y, acc[n][1]);
            acc[n][2] = fmaf(xv.x, w0.z, acc[n][2]);
            acc[n][2] = fmaf(xv.y, w1.z, acc[n][2]);
            acc[n][2] = fmaf(xv.z, w2.z, acc[n][2]);
            acc[n][2] = fmaf(xv.w, w3.z, acc[n][2]);
            acc[n][3] = fmaf(xv.x, w0.w, acc[n][3]);
            acc[n][3] = fmaf(xv.y, w1.w, acc[n][3]);
            acc[n][3] = fmaf(xv.z, w2.w, acc[n][3]);
            acc[n][3] = fmaf(xv.w, w3.w, acc[n][3]);
        }
    }
    bf16_t* ob = (mat == 0 ? kb : (mat == 1 ? qb : vb));
#pragma unroll
    for (int n = 0; n < 8; ++n) {
        int nid = sids[lt * 8 + n];
        if (nid >= 0) {
            ushort4 o4;
            o4.x = f2bf(acc[n][0]); o4.y = f2bf(acc[n][1]);
            o4.z = f2bf(acc[n][2]); o4.w = f2bf(acc[n][3]);
            *(ushort4*)(ob + (size_t)nid * DIM + colq * 4) = o4;
        }
    }
}

// ======================= K2: per-edge attention logits (v4, bf16 in) ==========

__global__ __launch_bounds__(256) void k_edge_a4(
    const bf16_t* __restrict__ kbuf, const bf16_t* __restrict__ qbuf,
    const int* __restrict__ esrc_s, const int* __restrict__ edst_s,
    const int* __restrict__ beg6,
    const float* __restrict__ rel_att, const float* __restrict__ rel_pri,
    float* __restrict__ a_ws, int nE) {
    __shared__ float A2[2][8 * 260];   // 2 r-slots, 8 heads, 16x16 each (stride 260)
    __shared__ float pri[2][8];
    __shared__ int rb_s[R_TYPES + 1];
    __shared__ int r01[2];
    int b = blockIdx.x;
    int e0 = b * 32;
    int tid = threadIdx.x;
    int nHere = nE - e0; if (nHere > 32) nHere = 32;
    if (nHere <= 0) return;
    if (tid < R_TYPES) rb_s[tid] = beg6[tid * N_NODES];   // start of relation r
    if (tid == R_TYPES) rb_s[R_TYPES] = nE;
    __syncthreads();
    if (tid == 0) {
        int rA = 0, rB = 0;
        int eL = e0 + nHere - 1;
#pragma unroll
        for (int r = 1; r < R_TYPES; ++r) {
            if (e0 >= rb_s[r]) rA = r;
            if (eL >= rb_s[r]) rB = r;
        }
        r01[0] = rA; r01[1] = rB;
    }
    __syncthreads();
    int r0 = r01[0], r1 = r01[1];
    int bnd = rb_s[r0 + 1];                   // entries >= bnd belong to r1
    for (int idx = tid; idx < 2 * 2048; idx += 256) {
        int slot = idx >> 11;
        if (slot == 1 && r1 == r0) break;
        int rem = idx & 2047;
        int h = rem >> 8, dj = rem & 255;
        int rr = slot ? r1 : r0;
        A2[slot][h * 260 + dj] = rel_att[(h * R_TYPES + rr) * 256 + dj];
    }
    if (tid < 16) {
        int slot = tid >> 3, h = tid & 7;
        pri[slot][h] = rel_pri[h * R_TYPES + (slot ? r1 : r0)] * 0.25f;
    }
    __syncthreads();
    int el = tid >> 3;
    int h  = tid & 7;
    int q2 = e0 + el;
    if (q2 >= nE) return;
    int s = esrc_s[q2], dn = edst_s[q2];
    int slot = (q2 >= bnd) ? 1 : 0;
    // 16 bf16 = 32 B per row-segment, 32B-aligned -> two uint4 loads each
    const uint4* kp = (const uint4*)(kbuf + (size_t)s  * DIM + h * 16);
    const uint4* qp = (const uint4*)(qbuf + (size_t)dn * DIM + h * 16);
    uint4 ka = kp[0], kb4 = kp[1];
    uint4 qa = qp[0], qb4 = qp[1];
    float kk[16], qq[16];
    bf2x(ka.x,  kk[0],  kk[1]);  bf2x(ka.y,  kk[2],  kk[3]);
    bf2x(ka.z,  kk[4],  kk[5]);  bf2x(ka.w,  kk[6],  kk[7]);
    bf2x(kb4.x, kk[8],  kk[9]);  bf2x(kb4.y, kk[10], kk[11]);
    bf2x(kb4.z, kk[12], kk[13]); bf2x(kb4.w, kk[14], kk[15]);
    bf2x(qa.x,  qq[0],  qq[1]);  bf2x(qa.y,  qq[2],  qq[3]);
    bf2x(qa.z,  qq[4],  qq[5]);  bf2x(qa.w,  qq[6],  qq[7]);
    bf2x(qb4.x, qq[8],  qq[9]);  bf2x(qb4.y, qq[10], qq[11]);
    bf2x(qb4.z, qq[12], qq[13]); bf2x(qb4.w, qq[14], qq[15]);
    const float4* A4 = (const float4*)&A2[slot][h * 260];
    float accj[16];
#pragma unroll
    for (int j = 0; j < 16; ++j) accj[j] = 0.f;
#pragma unroll
    for (int d = 0; d < 16; ++d) {
        float kd = kk[d];
#pragma unroll
        for (int jj = 0; jj < 4; ++jj) {
            float4 a4 = A4[d * 4 + jj];
            accj[jj * 4 + 0] = fmaf(kd, a4.x, accj[jj * 4 + 0]);
            accj[jj * 4 + 1] = fmaf(kd, a4.y, accj[jj * 4 + 1]);
            accj[jj * 4 + 2] = fmaf(kd, a4.z, accj[jj * 4 + 2]);
            accj[jj * 4 + 3] = fmaf(kd, a4.w, accj[jj * 4 + 3]);
        }
    }
    float acc = 0.f;
#pragma unroll
    for (int j = 0; j < 16; ++j) acc = fmaf(accj[j], qq[j], acc);
    a_ws[(size_t)q2 * 8 + h] = acc * pri[slot][h];   // coalesced (own position)
}

// ======================= K3: per-node softmax + aggregation (v10, bf16 v) =====
// agg8 structure (best byte/occupancy ratio) with bf16 v-rows: 256 B/row gather.

__global__ __launch_bounds__(256) void k_aggregate10(
    const bf16_t* __restrict__ vbuf, const float* __restrict__ a_ws,
    const int* __restrict__ beg6, const int* __restrict__ esrc_s,
    const float* __restrict__ rel_msg,
    float* __restrict__ hacc, int n, int nE) {
    __shared__ float wsum[2][R_TYPES * 128];   // 6 KB
    __shared__ float exl[2][MAXB][H_HEADS];    // 1 KB
    __shared__ int   sl[2][MAXB];
    __shared__ int   rl[2][MAXB];
    __shared__ int   bb[2][2 * R_TYPES];       // beg[r], end[r]
    __shared__ int   cum[2][R_TYPES + 1];      // cumulative run lengths
    __shared__ int   dgmax_s;
    int tid = threadIdx.x;
    int nb = tid >> 7;
    int lane2 = tid & 127;
    int node = blockIdx.x * 2 + nb;
    bool valid = node < n;
    int h = lane2 >> 4;
    int d = lane2 & 15;
    if (lane2 < 2 * R_TYPES) {
        int rr = lane2 >= R_TYPES ? lane2 - R_TYPES : lane2;
        int key = rr * N_NODES + (valid ? node : 0);
        int val;
        if (lane2 < R_TYPES) val = valid ? beg6[key] : 0;
        else                 val = valid ? ((key + 1 < NKEYS) ? beg6[key + 1] : nE) : 0;
        bb[nb][lane2] = val;
    }
    if (tid == 0) dgmax_s = 0;
    __syncthreads();
    if (lane2 == 0) {
        int c = 0;
#pragma unroll
        for (int rr = 0; rr < R_TYPES; ++rr) {
            cum[nb][rr] = c;
            c += bb[nb][R_TYPES + rr] - bb[nb][rr];
        }
        cum[nb][R_TYPES] = c;
        atomicMax(&dgmax_s, c);
    }
    __syncthreads();
    int dg = cum[nb][R_TYPES];
    int dgmax = dgmax_s;

    float* wsn = &wsum[nb][0];
#pragma unroll
    for (int rr = 0; rr < R_TYPES; ++rr) wsn[rr * 128 + lane2] = 0.f;

    float den = 0.f;
    float racc = 0.f;
    int rcur = -1;
    int js = lane2 >> 3;        // staging edge slot 0..15
    int hs = lane2 & 7;         // staging head

    for (int base = 0; base < dgmax; base += MAXB) {
        __syncthreads();        // previous batch's readers done
        // ---- phase 1: stage up to 16 edges (exp in parallel) ----
        int jj = base + js;
        if (jj < dg) {
            int rr = 0;
#pragma unroll
            for (int q = 1; q < R_TYPES; ++q) if (jj >= cum[nb][q]) rr = q;
            int p = bb[nb][rr] + (jj - cum[nb][rr]);
            exl[nb][js][hs] = __expf(a_ws[(size_t)p * 8 + hs] - SM_SHIFT);
            if (hs == 0) { sl[nb][js] = esrc_s[p]; rl[nb][js] = rr; }
        }
        __syncthreads();
        // ---- phase 2: accumulate (independent bf16 v-loads, unroll for MLP) ----
        int cnt = dg - base; if (cnt > MAXB) cnt = MAXB; if (cnt < 0) cnt = 0;
#pragma unroll 4
        for (int j = 0; j < cnt; ++j) {
            int r = rl[nb][j];                     // wave-uniform broadcast
            if (r != rcur) {
                if (rcur >= 0) wsn[rcur * 128 + lane2] += racc;
                racc = 0.f;
                rcur = r;
            }
            float ex = exl[nb][j][h];
            den += ex;
            float vv = bf2f(vbuf[(size_t)sl[nb][j] * DIM + lane2]);
            racc = fmaf(ex, vv, racc);
        }
    }
    if (rcur >= 0) wsn[rcur * 128 + lane2] += racc;
    __syncthreads();

    // epilogue: out[h][d] = (1/den) * sum_r sum_dp bucket[r][h][dp] * M[h][r][dp][d]
    float acc = 0.f;
#pragma unroll
    for (int rr = 0; rr < R_TYPES; ++rr) {
        const float*  M   = rel_msg + ((size_t)h * R_TYPES + rr) * 256;
        const float4* blr = (const float4*)&wsn[rr * 128 + h * 16];
#pragma unroll
        for (int dq = 0; dq < 4; ++dq) {
            float4 bv = blr[dq];
            acc = fmaf(bv.x, M[(dq * 4 + 0) * 16 + d], acc);
            acc = fmaf(bv.y, M[(dq * 4 + 1) * 16 + d], acc);
            acc = fmaf(bv.z, M[(dq * 4 + 2) * 16 + d], acc);
            acc = fmaf(bv.w, M[(dq * 4 + 3) * 16 + d], acc);
        }
    }
    if (valid)
        hacc[(size_t)node * DIM + lane2] = acc / fmaxf(den, 1e-9f);
}

// ======================= K4: tiled Wa + gate + residual + LayerNorm ===========

__global__ __launch_bounds__(256) void k_final_gemm(
    const float* __restrict__ x, const int* __restrict__ nlist,
    const int* __restrict__ tile_type, const int* __restrict__ ntiles_g,
    const float* __restrict__ Wa, const float* __restrict__ skip,
    const float* __restrict__ gamma, const float* __restrict__ beta,
    float* __restrict__ out) {
    __shared__ float hs[BN][DIM];
    __shared__ float ys[BN][DIM];
    __shared__ int sids[BN];
    __shared__ float mred[BN], ired[BN];
    int b = blockIdx.x;
    if (b >= *ntiles_g) return;
    int tid = threadIdx.x;
    if (tid < BN) sids[tid] = nlist[b * BN + tid];
    __syncthreads();
    for (int idx = tid; idx < BN * DIM; idx += 256) {
        int row = idx >> 7, col = idx & 127;
        int nid = sids[row];
        hs[row][col] = (nid >= 0) ? out[(size_t)nid * DIM + col] : 0.f;
    }
    __syncthreads();
    int t = tile_type[b];
    int half = tid >> 7, col = tid & 127;
    const float* W = Wa + (size_t)t * DIM * DIM;
    float acc[8];
#pragma unroll
    for (int n = 0; n < 8; ++n) acc[n] = 0.f;
#pragma unroll 4
    for (int d = 0; d < DIM; ++d) {
        float w = W[d * DIM + col];
#pragma unroll
        for (int n = 0; n < 8; ++n) acc[n] = fmaf(hs[half * 8 + n][d], w, acc[n]);
    }
    float gte = 1.f / (1.f + __expf(-skip[t]));
#pragma unroll
    for (int n = 0; n < 8; ++n) {
        int row = half * 8 + n;
        int nid = sids[row];
        float xv = (nid >= 0) ? x[(size_t)nid * DIM + col] : 0.f;
        ys[row][col] = xv * (2.f - gte) + acc[n] * gte;
    }
    __syncthreads();
    int ng = tid >> 4, l16 = tid & 15;
    float s = 0.f, s2 = 0.f;
#pragma unroll
    for (int k2 = 0; k2 < 8; ++k2) {
        float yv = ys[ng][l16 + 16 * k2];
        s += yv; s2 += yv * yv;
    }
#pragma unroll
    for (int m = 1; m < 16; m <<= 1) {
        s  += __shfl_xor(s, m, 64);
        s2 += __shfl_xor(s2, m, 64);
    }
    if (l16 == 0) {
        float mu = s * (1.f / DIM);
        float var = s2 * (1.f / DIM) - mu * mu;
        mred[ng] = mu;
        ired[ng] = rsqrtf(var + 1e-5f);
    }
    __syncthreads();
    float gm = gamma[col], bt = beta[col];
#pragma unroll
    for (int n = 0; n < 8; ++n) {
        int row = half * 8 + n;
        int nid = sids[row];
        if (nid >= 0)
            out[(size_t)nid * DIM + col] = (ys[row][col] - mred[row]) * ired[row] * gm + bt;
    }
}

// ======================= launcher =======================

extern "C" void kernel_launch(void* const* d_in, const int* in_sizes, int n_in,
                              void* d_out, int out_size, void* d_ws, size_t ws_size,
                              hipStream_t stream) {
    const float* x       = (const float*)d_in[0];
    const int*   src     = (const int*)d_in[1];
    const int*   dst     = (const int*)d_in[2];
    const int*   ntype   = (const int*)d_in[3];
    const int*   etype   = (const int*)d_in[4];
    const float* Wk      = (const float*)d_in[5];
    const float* Wq      = (const float*)d_in[6];
    const float* Wv      = (const float*)d_in[7];
    const float* Wa      = (const float*)d_in[8];
    const float* rel_pri = (const float*)d_in[9];
    const float* rel_att = (const float*)d_in[10];
    const float* rel_msg = (const float*)d_in[11];
    const float* skip    = (const float*)d_in[12];
    const float* gamma   = (const float*)d_in[13];
    const float* beta    = (const float*)d_in[14];
    float* out = (float*)d_out;

    const int N = N_NODES, E = N_EDGES;

    // workspace layout (floats/ints first, bf16 buffers last)
    char* ws = (char*)d_ws;
    float* a_ws = (float*)ws;                          // E*8 floats
    int* deg6    = (int*)(a_ws + (size_t)E * H_HEADS); // NKEYS
    int* beg6    = deg6 + NKEYS;                       // NKEYS
    int* cursor6 = beg6 + NKEYS;                       // NKEYS
    int* partial6 = cursor6 + NKEYS;                   // NBLK_K
    int* esrc_s  = partial6 + NBLK_K;                  // E
    int* edst_s  = esrc_s + E;                         // E
    int* tcnt    = edst_s + E;                         // 4
    int* pbase   = tcnt + T_TYPES;                     // 4
    int* ntiles  = pbase + T_TYPES;                    // 1
    int* tile_type = ntiles + 1;                       // MAX_TILES
    int* nlist   = tile_type + MAX_TILES;              // MAX_TILES*BN
    int* wpos    = nlist + (size_t)MAX_TILES * BN;     // N
    bf16_t* kb   = (bf16_t*)(wpos + N);                // N*DIM bf16
    bf16_t* qb   = kb + (size_t)N * DIM;               // N*DIM
    bf16_t* vb   = qb + (size_t)N * DIM;               // N*DIM

    const int nbScan = (N + 255) / 256;

    // r-major (r,dst)-keyed CSR build (single sort serves edge_a AND aggregate)
    hipMemsetAsync(deg6, 0, (size_t)NKEYS * sizeof(int), stream);
    k_count6<<<(E + 255) / 256, 256, 0, stream>>>(dst, etype, deg6, E);
    k_scanA<<<NBLK_K, 256, 0, stream>>>(deg6, beg6, partial6, NKEYS);
    k_rscan<<<1, 256, 0, stream>>>(partial6, NBLK_K);
    k_scanC2<<<NBLK_K, 256, 0, stream>>>(beg6, partial6, cursor6, NKEYS);
    k_scatter6<<<(E + 255) / 256, 256, 0, stream>>>(
        src, dst, etype, cursor6, esrc_s, edst_s, E);

    // node type buckets (padded 16-node tiles)
    hipMemsetAsync(tcnt, 0, T_TYPES * sizeof(int), stream);
    k_tcount_agg<<<nbScan, 256, 0, stream>>>(ntype, tcnt, wpos, N);
    k_tsetup<<<1, 256, 0, stream>>>(tcnt, pbase, ntiles, tile_type);
    hipMemsetAsync(nlist, 0xFF, (size_t)MAX_TILES * BN * sizeof(int), stream);
    k_tscatter2<<<nbScan, 256, 0, stream>>>(ntype, wpos, pbase, nlist, N);

    // projections (tiled per-type GEMM, bf16 outputs)
    k_kqv_gemm4<<<MAX_TILES, 192, 0, stream>>>(
        x, nlist, tile_type, ntiles, Wk, Wq, Wv, kb, qb, vb);

    // edge logits (bf16 k/q gather, f32 compute)
    k_edge_a4<<<(E + 31) / 32, 256, 0, stream>>>(
        kb, qb, esrc_s, edst_s, beg6, rel_att, rel_pri, a_ws, E);

    // per-node softmax + message aggregation -> d_out (scratch)
    k_aggregate10<<<(N + 1) / 2, 256, 0, stream>>>(
        vb, a_ws, beg6, esrc_s, rel_msg, out, N, E);

    // output projection + gate + residual + LayerNorm (in place on d_out)
    k_final_gemm<<<MAX_TILES, 256, 0, stream>>>(
        x, nlist, tile_type, ntiles, Wa, skip, gamma, beta, out);
}

// Round 13
// 384.902 us; speedup vs baseline: 1.0675x; 1.0042x over previous
//
#include <hip/hip_runtime.h>
#include <math.h>

#define N_NODES 50000
#define N_EDGES 400000
#define H_HEADS 8
#define D_HEAD 16
#define R_TYPES 6
#define T_TYPES 4
#define DIM 128
#define BN 16                                      // nodes per GEMM tile
#define MAX_TILES ((N_NODES + BN - 1) / BN + T_TYPES)
#define NKEYS (N_NODES * R_TYPES)                  // 300000 (r,dst) buckets, r-major
#define NBLK_K ((NKEYS + 255) / 256)               // 1172
#define NBLK_N ((N_NODES + 255) / 256)             // 196
#define SM_SHIFT 8.0f                              // constant softmax shift

typedef unsigned short bf16_t;

__device__ __forceinline__ float bf2f(bf16_t u) {
    unsigned int v = ((unsigned int)u) << 16;
    return __int_as_float((int)v);
}
__device__ __forceinline__ bf16_t f2bf(float f) {
    unsigned int u = (unsigned int)__float_as_int(f);
    unsigned int lsb = (u >> 16) & 1u;
    u += 0x7fffu + lsb;                            // round-to-nearest-even
    return (bf16_t)(u >> 16);
}
__device__ __forceinline__ void bf2x(unsigned int u, float& a, float& b) {
    a = bf2f((bf16_t)(u & 0xffffu));
    b = bf2f((bf16_t)(u >> 16));
}
__device__ __forceinline__ unsigned int pk(float a, float b) {
    return (unsigned int)f2bf(a) | ((unsigned int)f2bf(b) << 16);
}

// ======================= generic scan pieces =======================

__global__ void k_scanA(const int* __restrict__ cnt, int* __restrict__ offs,
                        int* __restrict__ partial, int n) {
    __shared__ int tmp[256];
    int tid = threadIdx.x;
    int i = blockIdx.x * 256 + tid;
    int v = (i < n) ? cnt[i] : 0;
    tmp[tid] = v;
    __syncthreads();
    for (int o = 1; o < 256; o <<= 1) {
        int t = (tid >= o) ? tmp[tid - o] : 0;
        __syncthreads();
        tmp[tid] += t;
        __syncthreads();
    }
    if (i < n) offs[i] = tmp[tid] - v;           // exclusive within block
    if (tid == 255) partial[blockIdx.x] = tmp[255];
}

__global__ void k_rscan(int* __restrict__ a, int total) {
    __shared__ int tmp[256];
    __shared__ int carry_s;
    int tid = threadIdx.x;
    if (tid == 0) carry_s = 0;
    __syncthreads();
    for (int base = 0; base < total; base += 256) {
        int i = base + tid;
        int v = (i < total) ? a[i] : 0;
        tmp[tid] = v;
        __syncthreads();
        for (int o = 1; o < 256; o <<= 1) {
            int t = (tid >= o) ? tmp[tid - o] : 0;
            __syncthreads();
            tmp[tid] += t;
            __syncthreads();
        }
        int carry = carry_s;
        if (i < total) a[i] = carry + tmp[tid] - v;   // exclusive
        __syncthreads();
        if (tid == 255) carry_s = carry + tmp[255];
        __syncthreads();
    }
}

__global__ void k_scanC2(int* __restrict__ offs, const int* __restrict__ partial,
                         int* __restrict__ cursor, int n) {
    int i = blockIdx.x * 256 + threadIdx.x;
    if (i < n) {
        int v = offs[i] + partial[blockIdx.x];
        offs[i] = v;
        cursor[i] = v;
    }
}

// ======================= r-major (r,dst)-keyed CSR build =======================

__global__ void k_count6(const int* __restrict__ dst, const int* __restrict__ etype,
                         int* __restrict__ deg6, int n) {
    int e = blockIdx.x * blockDim.x + threadIdx.x;
    if (e < n) atomicAdd(&deg6[etype[e] * N_NODES + dst[e]], 1);
}

__global__ void k_countD(const int* __restrict__ dst, int* __restrict__ degD, int n) {
    int e = blockIdx.x * blockDim.x + threadIdx.x;
    if (e < n) atomicAdd(&degD[dst[e]], 1);
}

__global__ void k_scatter6(const int* __restrict__ src, const int* __restrict__ dst,
                           const int* __restrict__ etype, int* __restrict__ cursor6,
                           int* __restrict__ esrc_s, int* __restrict__ edst_s, int n) {
    int e = blockIdx.x * blockDim.x + threadIdx.x;
    if (e < n) {
        int key = etype[e] * N_NODES + dst[e];
        int pos = atomicAdd(&cursor6[key], 1);
        esrc_s[pos] = src[e];
        edst_s[pos] = dst[e];
    }
}

// per-CSR-position dst-major write slot
__global__ void k_dpos(const int* __restrict__ edst_s, int* __restrict__ cursorD,
                       int* __restrict__ dpos, int n) {
    int p = blockIdx.x * blockDim.x + threadIdx.x;
    if (p < n) dpos[p] = atomicAdd(&cursorD[edst_s[p]], 1);
}

// ======================= node type bucketing (padded 16-node tiles) ===========

__global__ void k_tcount_agg(const int* __restrict__ ntype, int* __restrict__ tcnt,
                             int* __restrict__ wpos, int n) {
    __shared__ int hist[T_TYPES];
    __shared__ int base[T_TYPES];
    int tid = threadIdx.x;
    if (tid < T_TYPES) hist[tid] = 0;
    __syncthreads();
    int i = blockIdx.x * 256 + tid;
    int t = 0, rank = 0;
    if (i < n) {
        t = ntype[i];
        rank = atomicAdd(&hist[t], 1);
    }
    __syncthreads();
    if (tid < T_TYPES)
        base[tid] = (hist[tid] > 0) ? atomicAdd(&tcnt[tid], hist[tid]) : 0;
    __syncthreads();
    if (i < n) wpos[i] = base[t] + rank;
}

__global__ void k_tsetup(const int* __restrict__ tcnt, int* __restrict__ pbase,
                         int* __restrict__ ntiles_g, int* __restrict__ tile_type) {
    __shared__ int off[T_TYPES + 1];
    if (threadIdx.x == 0) {
        int o = 0;
        for (int t = 0; t < T_TYPES; ++t) {
            off[t] = o;
            pbase[t] = o * BN;
            o += (tcnt[t] + BN - 1) / BN;
        }
        off[T_TYPES] = o;
        *ntiles_g = o;
    }
    __syncthreads();
    int total = off[T_TYPES];
    for (int i = threadIdx.x; i < total; i += blockDim.x) {
        int t = 0;
        while (t < T_TYPES - 1 && i >= off[t + 1]) ++t;
        tile_type[i] = t;
    }
}

__global__ void k_tscatter2(const int* __restrict__ ntype, const int* __restrict__ wpos,
                            const int* __restrict__ pbase, int* __restrict__ nlist, int n) {
    int i = blockIdx.x * 256 + threadIdx.x;
    if (i < n) nlist[pbase[ntype[i]] + wpos[i]] = i;
}

// ======================= K1: tiled typed-linear k,q,v (bf16 out) ==========

__global__ __launch_bounds__(192) void k_kqv_gemm4(
    const float* __restrict__ x, const int* __restrict__ nlist,
    const int* __restrict__ tile_type, const int* __restrict__ ntiles_g,
    const float* __restrict__ Wk, const float* __restrict__ Wq,
    const float* __restrict__ Wv,
    bf16_t* __restrict__ kb, bf16_t* __restrict__ qb, bf16_t* __restrict__ vb) {
    __shared__ float xs[BN][DIM];   // 8 KB
    __shared__ int sids[BN];
    int b = blockIdx.x;
    if (b >= *ntiles_g) return;
    int tid = threadIdx.x;
    if (tid < BN) sids[tid] = nlist[b * BN + tid];
    __syncthreads();
    for (int idx = tid; idx < BN * (DIM / 4); idx += 192) {
        int row = idx >> 5;
        int q4 = idx & 31;
        int nid = sids[row];
        float4 v4 = make_float4(0.f, 0.f, 0.f, 0.f);
        if (nid >= 0) v4 = *(const float4*)(x + (size_t)nid * DIM + q4 * 4);
        *(float4*)(&xs[row][q4 * 4]) = v4;
    }
    __syncthreads();
    int lt = tid / 96;
    int wi = tid % 96;
    int mat = wi >> 5;
    int colq = wi & 31;
    int t = tile_type[b];
    const float* W = (mat == 0 ? Wk : (mat == 1 ? Wq : Wv))
                     + (size_t)t * DIM * DIM + colq * 4;
    float acc[8][4];
#pragma unroll
    for (int n = 0; n < 8; ++n) {
        acc[n][0] = 0.f; acc[n][1] = 0.f; acc[n][2] = 0.f; acc[n][3] = 0.f;
    }
    const float* xbase = &xs[lt * 8][0];
    for (int dq = 0; dq < 32; ++dq) {
        float4 w0 = *(const float4*)(W + (size_t)(dq * 4 + 0) * DIM);
        float4 w1 = *(const float4*)(W + (size_t)(dq * 4 + 1) * DIM);
        float4 w2 = *(const float4*)(W + (size_t)(dq * 4 + 2) * DIM);
        float4 w3 = *(const float4*)(W + (size_t)(dq * 4 + 3) * DIM);
#pragma unroll
        for (int n = 0; n < 8; ++n) {
            float4 xv = *(const float4*)(xbase + n * DIM + dq * 4);
            acc[n][0] = fmaf(xv.x, w0.x, acc[n][0]);
            acc[n][0] = fmaf(xv.y, w1.x, acc[n][0]);
            acc[n][0] = fmaf(xv.z, w2.x, acc[n][0]);
            acc[n][0] = fmaf(xv.w, w3.x, acc[n][0]);
            acc[n][1] = fmaf(xv.x, w0.y, acc[n][1]);
            acc[n][1] = fmaf(xv.y, w1.y, acc[n][1]);
            acc[n][1] = fmaf(xv.z, w2.y, acc[n][1]);
            acc[n][1] = fmaf(xv.w, w3.y, acc[n][1]);
            acc[n][2] = fmaf(xv.x, w0.z, acc[n][2]);
            acc[n][2] = fmaf(xv.y, w1.z, acc[n][2]);
            acc[n][2] = fmaf(xv.z, w2.z, acc[n][2]);
            acc[n][2] = fmaf(xv.w, w3.z, acc[n][2]);
            acc[n][3] = fmaf(xv.x, w0.w, acc[n][3]);
            acc[n][3] = fmaf(xv.y, w1.w, acc[n][3]);
            acc[n][3] = fmaf(xv.z, w2.w, acc[n][3]);
            acc[n][3] = fmaf(xv.w, w3.w, acc[n][3]);
        }
    }
    bf16_t* ob = (mat == 0 ? kb : (mat == 1 ? qb : vb));
#pragma unroll
    for (int n = 0; n < 8; ++n) {
        int nid = sids[lt * 8 + n];
        if (nid >= 0) {
            ushort4 o4;
            o4.x = f2bf(acc[n][0]); o4.y = f2bf(acc[n][1]);
            o4.z = f2bf(acc[n][2]); o4.w = f2bf(acc[n][3]);
            *(ushort4*)(ob + (size_t)nid * DIM + colq * 4) = o4;
        }
    }
}

// ======================= K2: fused edge kernel ================================
// Per (edge,h): a = (k A[h,r]) . q * pri; ex = exp(a - SHIFT); m = ex * (v M[h,r]).
// Writes ex (f32) and m (bf16, 16 elems) at the edge's DST-MAJOR position ->
// the aggregate kernel becomes a pure sequential stream. A and M wave-uniform
// (r-sorted CSR), staged in LDS with the bank-friendly stride-260 layout.

__global__ __launch_bounds__(256) void k_edge_m(
    const bf16_t* __restrict__ kbuf, const bf16_t* __restrict__ qbuf,
    const bf16_t* __restrict__ vbuf,
    const int* __restrict__ esrc_s, const int* __restrict__ edst_s,
    const int* __restrict__ beg6, const int* __restrict__ dpos,
    const float* __restrict__ rel_att, const float* __restrict__ rel_msg,
    const float* __restrict__ rel_pri,
    float* __restrict__ ex_out, bf16_t* __restrict__ m_out, int nE) {
    __shared__ float A2[2][8 * 260];   // 16.6 KB
    __shared__ float M2[2][8 * 260];   // 16.6 KB
    __shared__ float pri[2][8];
    __shared__ int rb_s[R_TYPES + 1];
    __shared__ int r01[2];
    int b = blockIdx.x;
    int e0 = b * 32;
    int tid = threadIdx.x;
    int nHere = nE - e0; if (nHere > 32) nHere = 32;
    if (nHere <= 0) return;
    if (tid < R_TYPES) rb_s[tid] = beg6[tid * N_NODES];
    if (tid == R_TYPES) rb_s[R_TYPES] = nE;
    __syncthreads();
    if (tid == 0) {
        int rA = 0, rB = 0;
        int eL = e0 + nHere - 1;
#pragma unroll
        for (int r = 1; r < R_TYPES; ++r) {
            if (e0 >= rb_s[r]) rA = r;
            if (eL >= rb_s[r]) rB = r;
        }
        r01[0] = rA; r01[1] = rB;
    }
    __syncthreads();
    int r0 = r01[0], r1 = r01[1];
    int bnd = rb_s[r0 + 1];                   // entries >= bnd belong to r1
    for (int idx = tid; idx < 2 * 2048; idx += 256) {
        int slot = idx >> 11;
        if (slot == 1 && r1 == r0) break;
        int rem = idx & 2047;
        int h = rem >> 8, dj = rem & 255;
        int rr = slot ? r1 : r0;
        A2[slot][h * 260 + dj] = rel_att[(h * R_TYPES + rr) * 256 + dj];
        M2[slot][h * 260 + dj] = rel_msg[(h * R_TYPES + rr) * 256 + dj];
    }
    if (tid < 16) {
        int slot = tid >> 3, h = tid & 7;
        pri[slot][h] = rel_pri[h * R_TYPES + (slot ? r1 : r0)] * 0.25f;
    }
    __syncthreads();
    int el = tid >> 3;
    int h  = tid & 7;
    int q2 = e0 + el;
    if (q2 >= nE) return;
    int s = esrc_s[q2], dn = edst_s[q2];
    int slot = (q2 >= bnd) ? 1 : 0;
    const uint4* kp = (const uint4*)(kbuf + (size_t)s  * DIM + h * 16);
    const uint4* qp = (const uint4*)(qbuf + (size_t)dn * DIM + h * 16);
    const uint4* vp = (const uint4*)(vbuf + (size_t)s  * DIM + h * 16);
    uint4 ka = kp[0], kb4 = kp[1];
    uint4 qa = qp[0], qb4 = qp[1];
    uint4 va = vp[0], vb4 = vp[1];
    float kk[16], qq[16], vv[16];
    bf2x(ka.x,  kk[0],  kk[1]);  bf2x(ka.y,  kk[2],  kk[3]);
    bf2x(ka.z,  kk[4],  kk[5]);  bf2x(ka.w,  kk[6],  kk[7]);
    bf2x(kb4.x, kk[8],  kk[9]);  bf2x(kb4.y, kk[10], kk[11]);
    bf2x(kb4.z, kk[12], kk[13]); bf2x(kb4.w, kk[14], kk[15]);
    bf2x(qa.x,  qq[0],  qq[1]);  bf2x(qa.y,  qq[2],  qq[3]);
    bf2x(qa.z,  qq[4],  qq[5]);  bf2x(qa.w,  qq[6],  qq[7]);
    bf2x(qb4.x, qq[8],  qq[9]);  bf2x(qb4.y, qq[10], qq[11]);
    bf2x(qb4.z, qq[12], qq[13]); bf2x(qb4.w, qq[14], qq[15]);
    bf2x(va.x,  vv[0],  vv[1]);  bf2x(va.y,  vv[2],  vv[3]);
    bf2x(va.z,  vv[4],  vv[5]);  bf2x(va.w,  vv[6],  vv[7]);
    bf2x(vb4.x, vv[8],  vv[9]);  bf2x(vb4.y, vv[10], vv[11]);
    bf2x(vb4.z, vv[12], vv[13]); bf2x(vb4.w, vv[14], vv[15]);

    // QK^T: accj[j] = sum_d k_d A[d][j];  a = sum_j accj[j] q_j
    const float4* A4 = (const float4*)&A2[slot][h * 260];
    float accj[16];
#pragma unroll
    for (int j = 0; j < 16; ++j) accj[j] = 0.f;
#pragma unroll
    for (int d = 0; d < 16; ++d) {
        float kd = kk[d];
#pragma unroll
        for (int jj = 0; jj < 4; ++jj) {
            float4 a4 = A4[d * 4 + jj];
            accj[jj * 4 + 0] = fmaf(kd, a4.x, accj[jj * 4 + 0]);
            accj[jj * 4 + 1] = fmaf(kd, a4.y, accj[jj * 4 + 1]);
            accj[jj * 4 + 2] = fmaf(kd, a4.z, accj[jj * 4 + 2]);
            accj[jj * 4 + 3] = fmaf(kd, a4.w, accj[jj * 4 + 3]);
        }
    }
    float a = 0.f;
#pragma unroll
    for (int j = 0; j < 16; ++j) a = fmaf(accj[j], qq[j], a);
    float ex = __expf(a * pri[slot][h] - SM_SHIFT);

    // message: m[j] = ex * sum_d v_d M[d][j]
    const float4* M4 = (const float4*)&M2[slot][h * 260];
    float mj[16];
#pragma unroll
    for (int j = 0; j < 16; ++j) mj[j] = 0.f;
#pragma unroll
    for (int d = 0; d < 16; ++d) {
        float vd = vv[d];
#pragma unroll
        for (int jj = 0; jj < 4; ++jj) {
            float4 m4 = M4[d * 4 + jj];
            mj[jj * 4 + 0] = fmaf(vd, m4.x, mj[jj * 4 + 0]);
            mj[jj * 4 + 1] = fmaf(vd, m4.y, mj[jj * 4 + 1]);
            mj[jj * 4 + 2] = fmaf(vd, m4.z, mj[jj * 4 + 2]);
            mj[jj * 4 + 3] = fmaf(vd, m4.w, mj[jj * 4 + 3]);
        }
    }
    int dp = dpos[q2];
    ex_out[(size_t)dp * 8 + h] = ex;
    uint4 o0, o1;
    o0.x = pk(ex * mj[0],  ex * mj[1]);  o0.y = pk(ex * mj[2],  ex * mj[3]);
    o0.z = pk(ex * mj[4],  ex * mj[5]);  o0.w = pk(ex * mj[6],  ex * mj[7]);
    o1.x = pk(ex * mj[8],  ex * mj[9]);  o1.y = pk(ex * mj[10], ex * mj[11]);
    o1.z = pk(ex * mj[12], ex * mj[13]); o1.w = pk(ex * mj[14], ex * mj[15]);
    uint4* op = (uint4*)(m_out + (size_t)dp * DIM + h * 16);
    op[0] = o0; op[1] = o1;
}

// ======================= K3: streaming aggregate ==============================
// Per node: edges contiguous in dst-major order. h = (sum m rows) / (sum ex).
// Pure sequential reads, no buckets, no M.

__global__ __launch_bounds__(256) void k_agg_stream(
    const bf16_t* __restrict__ m_out, const float* __restrict__ ex_out,
    const int* __restrict__ doffD, const int* __restrict__ degD,
    float* __restrict__ hacc, int n) {
    int tid = threadIdx.x;
    int nb = tid >> 7;
    int lane2 = tid & 127;
    int node = blockIdx.x * 2 + nb;
    if (node >= n) return;
    int h = lane2 >> 4;
    int off = doffD[node];
    int dg  = degD[node];
    float acc = 0.f, den = 0.f;
#pragma unroll 4
    for (int j = 0; j < dg; ++j) {
        den += ex_out[(size_t)(off + j) * 8 + h];                 // broadcast
        acc += bf2f(m_out[(size_t)(off + j) * DIM + lane2]);      // coalesced row
    }
    hacc[(size_t)node * DIM + lane2] = acc / fmaxf(den, 1e-9f);
}

// ======================= K4: tiled Wa + gate + residual + LayerNorm ===========

__global__ __launch_bounds__(256) void k_final_gemm(
    const float* __restrict__ x, const int* __restrict__ nlist,
    const int* __restrict__ tile_type, const int* __restrict__ ntiles_g,
    const float* __restrict__ Wa, const float* __restrict__ skip,
    const float* __restrict__ gamma, const float* __restrict__ beta,
    float* __restrict__ out) {
    __shared__ float hs[BN][DIM];
    __shared__ float ys[BN][DIM];
    __shared__ int sids[BN];
    __shared__ float mred[BN], ired[BN];
    int b = blockIdx.x;
    if (b >= *ntiles_g) return;
    int tid = threadIdx.x;
    if (tid < BN) sids[tid] = nlist[b * BN + tid];
    __syncthreads();
    for (int idx = tid; idx < BN * DIM; idx += 256) {
        int row = idx >> 7, col = idx & 127;
        int nid = sids[row];
        hs[row][col] = (nid >= 0) ? out[(size_t)nid * DIM + col] : 0.f;
    }
    __syncthreads();
    int t = tile_type[b];
    int half = tid >> 7, col = tid & 127;
    const float* W = Wa + (size_t)t * DIM * DIM;
    float acc[8];
#pragma unroll
    for (int n = 0; n < 8; ++n) acc[n] = 0.f;
#pragma unroll 4
    for (int d = 0; d < DIM; ++d) {
        float w = W[d * DIM + col];
#pragma unroll
        for (int n = 0; n < 8; ++n) acc[n] = fmaf(hs[half * 8 + n][d], w, acc[n]);
    }
    float gte = 1.f / (1.f + __expf(-skip[t]));
#pragma unroll
    for (int n = 0; n < 8; ++n) {
        int row = half * 8 + n;
        int nid = sids[row];
        float xv = (nid >= 0) ? x[(size_t)nid * DIM + col] : 0.f;
        ys[row][col] = xv * (2.f - gte) + acc[n] * gte;
    }
    __syncthreads();
    int ng = tid >> 4, l16 = tid & 15;
    float s = 0.f, s2 = 0.f;
#pragma unroll
    for (int k2 = 0; k2 < 8; ++k2) {
        float yv = ys[ng][l16 + 16 * k2];
        s += yv; s2 += yv * yv;
    }
#pragma unroll
    for (int m = 1; m < 16; m <<= 1) {
        s  += __shfl_xor(s, m, 64);
        s2 += __shfl_xor(s2, m, 64);
    }
    if (l16 == 0) {
        float mu = s * (1.f / DIM);
        float var = s2 * (1.f / DIM) - mu * mu;
        mred[ng] = mu;
        ired[ng] = rsqrtf(var + 1e-5f);
    }
    __syncthreads();
    float gm = gamma[col], bt = beta[col];
#pragma unroll
    for (int n = 0; n < 8; ++n) {
        int row = half * 8 + n;
        int nid = sids[row];
        if (nid >= 0)
            out[(size_t)nid * DIM + col] = (ys[row][col] - mred[row]) * ired[row] * gm + bt;
    }
}

// ======================= launcher =======================

extern "C" void kernel_launch(void* const* d_in, const int* in_sizes, int n_in,
                              void* d_out, int out_size, void* d_ws, size_t ws_size,
                              hipStream_t stream) {
    const float* x       = (const float*)d_in[0];
    const int*   src     = (const int*)d_in[1];
    const int*   dst     = (const int*)d_in[2];
    const int*   ntype   = (const int*)d_in[3];
    const int*   etype   = (const int*)d_in[4];
    const float* Wk      = (const float*)d_in[5];
    const float* Wq      = (const float*)d_in[6];
    const float* Wv      = (const float*)d_in[7];
    const float* Wa      = (const float*)d_in[8];
    const float* rel_pri = (const float*)d_in[9];
    const float* rel_att = (const float*)d_in[10];
    const float* rel_msg = (const float*)d_in[11];
    const float* skip    = (const float*)d_in[12];
    const float* gamma   = (const float*)d_in[13];
    const float* beta    = (const float*)d_in[14];
    float* out = (float*)d_out;

    const int N = N_NODES, E = N_EDGES;

    // workspace layout
    char* ws = (char*)d_ws;
    float* ex_out = (float*)ws;                         // E*8 f32 (12.8 MB)
    int* deg6    = (int*)(ex_out + (size_t)E * H_HEADS);// NKEYS
    int* beg6    = deg6 + NKEYS;                        // NKEYS
    int* cursor6 = beg6 + NKEYS;                        // NKEYS
    int* partial6 = cursor6 + NKEYS;                    // NBLK_K
    int* degD    = partial6 + NBLK_K;                   // N
    int* doffD   = degD + N;                            // N
    int* cursorD = doffD + N;                           // N
    int* partialD = cursorD + N;                        // NBLK_N
    int* dpos    = partialD + NBLK_N;                   // E
    int* esrc_s  = dpos + E;                            // E
    int* edst_s  = esrc_s + E;                          // E
    int* tcnt    = edst_s + E;                          // 4
    int* pbase   = tcnt + T_TYPES;                      // 4
    int* ntiles  = pbase + T_TYPES;                     // 1
    int* tile_type = ntiles + 1;                        // MAX_TILES
    int* nlist   = tile_type + MAX_TILES;               // MAX_TILES*BN
    int* wpos    = nlist + (size_t)MAX_TILES * BN;      // N
    bf16_t* kb   = (bf16_t*)(wpos + N);                 // N*DIM bf16
    bf16_t* qb   = kb + (size_t)N * DIM;                // N*DIM
    bf16_t* vb   = qb + (size_t)N * DIM;                // N*DIM
    bf16_t* m_out = vb + (size_t)N * DIM;               // E*DIM bf16 (102.4 MB)

    const int nbE = (E + 255) / 256;

    // r-major (r,dst)-keyed CSR build + dst-major degree/offset
    hipMemsetAsync(deg6, 0, (size_t)NKEYS * sizeof(int), stream);
    hipMemsetAsync(degD, 0, (size_t)N * sizeof(int), stream);
    k_count6<<<nbE, 256, 0, stream>>>(dst, etype, deg6, E);
    k_countD<<<nbE, 256, 0, stream>>>(dst, degD, E);
    k_scanA<<<NBLK_K, 256, 0, stream>>>(deg6, beg6, partial6, NKEYS);
    k_rscan<<<1, 256, 0, stream>>>(partial6, NBLK_K);
    k_scanC2<<<NBLK_K, 256, 0, stream>>>(beg6, partial6, cursor6, NKEYS);
    k_scanA<<<NBLK_N, 256, 0, stream>>>(degD, doffD, partialD, N);
    k_rscan<<<1, 256, 0, stream>>>(partialD, NBLK_N);
    k_scanC2<<<NBLK_N, 256, 0, stream>>>(doffD, partialD, cursorD, N);
    k_scatter6<<<nbE, 256, 0, stream>>>(
        src, dst, etype, cursor6, esrc_s, edst_s, E);
    k_dpos<<<nbE, 256, 0, stream>>>(edst_s, cursorD, dpos, E);

    // node type buckets (padded 16-node tiles)
    hipMemsetAsync(tcnt, 0, T_TYPES * sizeof(int), stream);
    k_tcount_agg<<<NBLK_N, 256, 0, stream>>>(ntype, tcnt, wpos, N);
    k_tsetup<<<1, 256, 0, stream>>>(tcnt, pbase, ntiles, tile_type);
    hipMemsetAsync(nlist, 0xFF, (size_t)MAX_TILES * BN * sizeof(int), stream);
    k_tscatter2<<<NBLK_N, 256, 0, stream>>>(ntype, wpos, pbase, nlist, N);

    // projections (tiled per-type GEMM, bf16 outputs)
    k_kqv_gemm4<<<MAX_TILES, 192, 0, stream>>>(
        x, nlist, tile_type, ntiles, Wk, Wq, Wv, kb, qb, vb);

    // fused edge kernel: QK^T, exp, M.v -> dst-major ex/m
    k_edge_m<<<(E + 31) / 32, 256, 0, stream>>>(
        kb, qb, vb, esrc_s, edst_s, beg6, dpos,
        rel_att, rel_msg, rel_pri, ex_out, m_out, E);

    // streaming per-node aggregate -> d_out (scratch)
    k_agg_stream<<<(N + 1) / 2, 256, 0, stream>>>(
        m_out, ex_out, doffD, degD, out, N);

    // output projection + gate + residual + LayerNorm (in place on d_out)
    k_final_gemm<<<MAX_TILES, 256, 0, stream>>>(
        x, nlist, tile_type, ntiles, Wa, skip, gamma, beta, out);
}